// Round 1
// baseline (175.893 us; speedup 1.0000x reference)
//
#include <hip/hip_runtime.h>
#include <hip/hip_fp16.h>

#define FH 240
#define FW 240
#define NSAMP 179   // 9 + 49 + 121
constexpr float IMG = 960.0f;

// ---------------- ws layout (floats) ----------------
static constexpr int WS_FMT   = 0;        // fmT fp16 [240][240][64] -> 1,843,200 float slots
static constexpr int WS_GPART = 1843200;  // gpartial [960][64]
static constexpr int WS_G     = 1904640;  // g [64] (pre-scaled by 1/57600)
static constexpr int WS_PERM  = 1904704;  // perm [4000] ints
static constexpr int WS_POOL  = 1908736;  // pooled [N][192]

// ---------- Kernel 1: blocks 0..959 transpose fm -> fp16 fmT + channel partials;
//                      block 960: counting-sort boxes by (cy,cx) buckets -> perm ----------
__global__ __launch_bounds__(256) void k_prep(const float* __restrict__ fm,
                                              __half* __restrict__ fmT,
                                              float* __restrict__ gpartial,
                                              const float* __restrict__ boxes,
                                              int* __restrict__ perm, int n) {
    __shared__ float tile[64][65];
    __shared__ int hist[256];
    __shared__ int offs[256];
    int bid = blockIdx.x;
    int tid = threadIdx.x;

    if (bid < 960) {
        int y  = bid >> 2;
        int x0 = (bid & 3) * 64;
        int lane = tid & 63;
        int wv   = tid >> 6;
        int x = x0 + lane;
        bool xin = (x < FW);
        #pragma unroll
        for (int k = 0; k < 16; ++k) {
            int c = wv + k * 4;
            tile[c][lane] = xin ? fm[c * (FH * FW) + y * FW + x] : 0.0f;
        }
        __syncthreads();

        if (tid < 64) {
            float s = 0.0f;
            #pragma unroll
            for (int i = 0; i < 64; ++i) s += tile[tid][i];
            gpartial[bid * 64 + tid] = s;
        }

        #pragma unroll
        for (int it = 0; it < 2; ++it) {
            int idx = tid + it * 256;       // 0..511
            int xl  = idx >> 3;             // 0..63
            int co  = (idx & 7) * 8;        // 0,8,...,56
            int xx  = x0 + xl;
            if (xx < FW) {
                union { float4 f4; __half2 h2[4]; } u;
                #pragma unroll
                for (int i = 0; i < 4; ++i)
                    u.h2[i] = __floats2half2_rn(tile[co + 2*i][xl], tile[co + 2*i + 1][xl]);
                *(float4*)&fmT[((size_t)(y * FW + xx)) * 64 + co] = u.f4;
            }
        }
    } else {
        // ---- counting sort of boxes by (cy, cx) 16x16 buckets ----
        hist[tid] = 0;
        __syncthreads();
        for (int i = tid; i < n; i += 256) {
            float cy = (boxes[i * 4 + 1] + boxes[i * 4 + 3]) * 0.5f;
            float cx = (boxes[i * 4 + 0] + boxes[i * 4 + 2]) * 0.5f;
            int by = min(15, max(0, (int)(cy * (16.0f / 960.0f))));
            int bx = min(15, max(0, (int)(cx * (16.0f / 960.0f))));
            atomicAdd(&hist[by * 16 + bx], 1);
        }
        __syncthreads();
        offs[tid] = hist[tid];
        __syncthreads();
        for (int st = 1; st < 256; st <<= 1) {
            int t2 = (tid >= st) ? offs[tid - st] : 0;
            __syncthreads();
            offs[tid] += t2;
            __syncthreads();
        }
        hist[tid] = offs[tid] - hist[tid];     // exclusive start per bucket
        __syncthreads();
        for (int i = tid; i < n; i += 256) {
            float cy = (boxes[i * 4 + 1] + boxes[i * 4 + 3]) * 0.5f;
            float cx = (boxes[i * 4 + 0] + boxes[i * 4 + 2]) * 0.5f;
            int by = min(15, max(0, (int)(cy * (16.0f / 960.0f))));
            int bx = min(15, max(0, (int)(cx * (16.0f / 960.0f))));
            int pos = atomicAdd(&hist[by * 16 + bx], 1);
            perm[pos] = i;
        }
    }
}

// ---------- Kernel 2: ROI bilinear pooling (unchanged) ----------
__device__ __forceinline__ void acc8(float* a, const __half* __restrict__ base,
                                     int off, int c8, float w) {
    float4 raw = *(const float4*)(base + off + c8);   // 8 fp16
    const __half2* h = (const __half2*)&raw;
    #pragma unroll
    for (int i = 0; i < 4; ++i) {
        float2 f = __half22float2(h[i]);
        a[2*i]     = fmaf(w, f.x, a[2*i]);
        a[2*i + 1] = fmaf(w, f.y, a[2*i + 1]);
    }
}

__global__ __launch_bounds__(256) void k_pool(const __half* __restrict__ fmT,
                                              const float* __restrict__ boxes,
                                              const int* __restrict__ perm,
                                              const float* __restrict__ gpartial,
                                              float* __restrict__ g,
                                              float* __restrict__ pooled) {
    __shared__ int   smp[NSAMP * 8];        // 5728 B
    __shared__ float part[64 * 33];         // 8448 B

    int tid = threadIdx.x;

    if (blockIdx.x == 0) {
        int c = tid & 63, q = tid >> 6;
        float s = 0.0f;
        for (int i = q * 240; i < q * 240 + 240; ++i) s += gpartial[i * 64 + c];
        part[tid] = s;
        __syncthreads();
        if (tid < 64)
            g[tid] = (part[tid] + part[64 + tid] + part[128 + tid] + part[192 + tid]) * (1.0f / 57600.0f);
        __syncthreads();
    }

    int box = perm[blockIdx.x];

    if (tid < NSAMP) {
        float bx1 = boxes[box * 4 + 0], by1 = boxes[box * 4 + 1];
        float bx2 = boxes[box * 4 + 2], by2 = boxes[box * 4 + 3];
        float x1n = (bx1 / IMG) * 2.0f - 1.0f;
        float y1n = (by1 / IMG) * 2.0f - 1.0f;
        float x2n = (bx2 / IMG) * 2.0f - 1.0f;
        float y2n = (by2 / IMG) * 2.0f - 1.0f;
        float cx = (x1n + x2n) * 0.5f, cy = (y1n + y2n) * 0.5f;
        float w2 = fmaxf(x2n - x1n, 1e-6f) * 0.5f;
        float h2 = fmaxf(y2n - y1n, 1e-6f) * 0.5f;
        int S, s;
        if (tid < 9)       { S = 3;  s = tid; }
        else if (tid < 58) { S = 7;  s = tid - 9; }
        else               { S = 11; s = tid - 58; }
        int i = s / S;
        int j = s - i * S;
        float Sf = (float)S;
        float bj = (2.0f * (float)j + 1.0f) / Sf - 1.0f;
        float bi = (2.0f * (float)i + 1.0f) / Sf - 1.0f;
        float gx = w2 * bj + cx;
        float gy = h2 * bi + cy;
        float ix = ((gx + 1.0f) * 240.0f - 1.0f) * 0.5f;
        float iy = ((gy + 1.0f) * 240.0f - 1.0f) * 0.5f;
        float x0f = floorf(ix), y0f = floorf(iy);
        float dx = ix - x0f,    dy = iy - y0f;
        int x0 = (int)x0f, y0 = (int)y0f;
        int x1 = x0 + 1,   y1 = y0 + 1;
        float inv = 1.0f / (Sf * Sf);
        float wx0 = (x0 >= 0 && x0 < FW) ? (1.0f - dx) : 0.0f;
        float wx1 = (x1 >= 0 && x1 < FW) ? dx          : 0.0f;
        float wy0 = (y0 >= 0 && y0 < FH) ? (1.0f - dy) : 0.0f;
        float wy1 = (y1 >= 0 && y1 < FH) ? dy          : 0.0f;
        int x0c = min(max(x0, 0), FW - 1), x1c = min(max(x1, 0), FW - 1);
        int y0c = min(max(y0, 0), FH - 1), y1c = min(max(y1, 0), FH - 1);
        int r0 = y0c * FW, r1 = y1c * FW;
        smp[tid * 8 + 0] = (r0 + x0c) * 64;
        smp[tid * 8 + 1] = (r0 + x1c) * 64;
        smp[tid * 8 + 2] = (r1 + x0c) * 64;
        smp[tid * 8 + 3] = (r1 + x1c) * 64;
        float* wp = (float*)&smp[tid * 8 + 4];
        wp[0] = wx0 * wy0 * inv;
        wp[1] = wx1 * wy0 * inv;
        wp[2] = wx0 * wy1 * inv;
        wp[3] = wx1 * wy1 * inv;
    }
    __syncthreads();

    int slot = tid >> 3, l = tid & 7, c8 = l << 3;
    const int start_[3] = {0, 9, 58};
    const int end_[3]   = {9, 58, NSAMP};

    #pragma unroll
    for (int sc = 0; sc < 3; ++sc) {
        float a[8];
        #pragma unroll
        for (int k = 0; k < 8; ++k) a[k] = 0.0f;
        for (int s = start_[sc] + slot; s < end_[sc]; s += 32) {
            int4   bo = *(const int4*)  &smp[s * 8];
            float4 wv = *(const float4*)&smp[s * 8 + 4];
            acc8(a, fmT, bo.x, c8, wv.x);
            acc8(a, fmT, bo.y, c8, wv.y);
            acc8(a, fmT, bo.z, c8, wv.z);
            acc8(a, fmT, bo.w, c8, wv.w);
        }
        #pragma unroll
        for (int i = 0; i < 8; ++i)
            part[(c8 + i) * 33 + slot] = a[i];
        __syncthreads();
        if (tid < 64) {
            float sum = 0.0f;
            #pragma unroll
            for (int q = 0; q < 32; ++q) sum += part[tid * 33 + q];
            pooled[(size_t)box * 192 + sc * 64 + tid] = sum;
        }
        __syncthreads();
    }
}

// ---------- Kernel 3: heads + final MLP ----------
// Rewrite: all weights streamed to LDS in 16 KB chunks via global_load_lds,
// double-buffered, depth-1 prefetch (issue chunk j+1; compute chunk j from LDS;
// __syncthreads drains). Inner loops touch only LDS+regs -> no global latency
// on the critical path. 14 chunks: W1 x2, W2 x2, P1 x8, P2 x2.
// LDS layout (floats):
//   [0      .. 8191 ]  wbuf[2][4096]  (two 16 KB weight chunk buffers)
//   [8192   .. 10271]  inp[2048] (pooled-order rows + g at 1536 + zeros)  ALIASED with
//                      cat[8][260] (written in S2 epilogue, after inp is dead)
//   [10272  .. 14495]  h1[32][132]    ALIASED with hid[8][132] (after h1 dead)
static constexpr int OFF_INP = 8192;
static constexpr int OFF_H1  = 10272;
static constexpr int LDS_FLOATS = 14496;   // 57,984 B -> 2 blocks/CU

__device__ __forceinline__ void gll16(const float* src, float* lds_dst) {
    __builtin_amdgcn_global_load_lds((const __attribute__((address_space(1))) void*)src,
                                     (__attribute__((address_space(3))) void*)lds_dst,
                                     16, 0, 0);
}
__device__ __forceinline__ void gll4(const float* src, float* lds_dst) {
    __builtin_amdgcn_global_load_lds((const __attribute__((address_space(1))) void*)src,
                                     (__attribute__((address_space(3))) void*)lds_dst,
                                     4, 0, 0);
}

__device__ __forceinline__ const float* chunk_ptr(int j, const float* W1, const float* W2,
                                                  const float* P1, const float* P2) {
    if (j < 2)  return W1 + j * 4096;
    if (j < 4)  return W2 + (j - 2) * 4096;
    if (j < 12) return P1 + (j - 4) * 4096;
    return P2 + (j - 12) * 4096;
}

__device__ __forceinline__ void issue_chunk(const float* src, float* dst, int tid) {
    #pragma unroll
    for (int i = 0; i < 4; ++i)
        gll16(src + i * 1024 + tid * 4, dst + i * 1024 + tid * 4);
}

__global__ __launch_bounds__(256) void k_mlp(const float* __restrict__ pooled,
                                             const float* __restrict__ g,
                                             const float* __restrict__ W1, const float* __restrict__ b1,
                                             const float* __restrict__ W2, const float* __restrict__ b2,
                                             const float* __restrict__ P1, const float* __restrict__ bp1,
                                             const float* __restrict__ P2, const float* __restrict__ bp2,
                                             float* __restrict__ out, int n) {
    __shared__ float lds[LDS_FLOATS];
    int tid = threadIdx.x;
    int box0 = blockIdx.x * 8;

    // ---- prologue: issue chunk 0 + stage inputs, then one barrier ----
    issue_chunk(chunk_ptr(0, W1, W2, P1, P2), &lds[0], tid);
    {
        const float* src = pooled + (size_t)box0 * 192;
        gll16(src + tid * 4, &lds[OFF_INP + tid * 4]);                     // 4096 B
        if (tid < 128) gll16(src + 1024 + tid * 4, &lds[OFF_INP + 1024 + tid * 4]); // 2048 B
        if (tid < 64)  gll4(g + tid, &lds[OFF_INP + 1536 + tid]);          // g row (row 24)
    }
    if (tid < 224) {                       // zero rows 25..31 (448 floats)
        lds[OFF_INP + 1600 + tid] = 0.0f;
        lds[OFF_INP + 1824 + tid] = 0.0f;
    }
    __syncthreads();                       // drains all global_load_lds

    // ================= S1: h1 = relu(inp @ W1 + b1)  (chunks 0,1; K=32 each) ==========
    {
        int c4 = (tid & 31) * 4;           // 32 col-groups x 4 cols = 128
        int r4 = (tid >> 5) * 4;           // 8 row-groups x 4 rows = 32
        int ro[4];
        #pragma unroll
        for (int rr = 0; rr < 4; ++rr) {
            int m = r4 + rr;
            ro[rr] = OFF_INP + ((m < 24) ? ((m & 7) * 192 + (m >> 3) * 64) : m * 64);
        }
        float acc[4][4] = {};
        #pragma unroll
        for (int cc = 0; cc < 2; ++cc) {
            int j = cc;
            issue_chunk(chunk_ptr(j + 1, W1, W2, P1, P2), &lds[((j + 1) & 1) * 4096], tid);
            const float* wb = &lds[(j & 1) * 4096];
            int kb = cc * 32;
            #pragma unroll
            for (int k = 0; k < 32; k += 4) {
                float4 a[4];
                #pragma unroll
                for (int rr = 0; rr < 4; ++rr) a[rr] = *(const float4*)&lds[ro[rr] + kb + k];
                #pragma unroll
                for (int kk = 0; kk < 4; ++kk) {
                    float4 w = *(const float4*)&wb[(k + kk) * 128 + c4];
                    #pragma unroll
                    for (int rr = 0; rr < 4; ++rr) {
                        float av = ((const float*)&a[rr])[kk];
                        acc[rr][0] = fmaf(av, w.x, acc[rr][0]);
                        acc[rr][1] = fmaf(av, w.y, acc[rr][1]);
                        acc[rr][2] = fmaf(av, w.z, acc[rr][2]);
                        acc[rr][3] = fmaf(av, w.w, acc[rr][3]);
                    }
                }
            }
            if (cc == 1) {   // epilogue before the chunk barrier
                float4 bb = *(const float4*)&b1[c4];
                #pragma unroll
                for (int rr = 0; rr < 4; ++rr) {
                    float4 o;
                    o.x = fmaxf(acc[rr][0] + bb.x, 0.0f);
                    o.y = fmaxf(acc[rr][1] + bb.y, 0.0f);
                    o.z = fmaxf(acc[rr][2] + bb.z, 0.0f);
                    o.w = fmaxf(acc[rr][3] + bb.w, 0.0f);
                    *(float4*)&lds[OFF_H1 + (r4 + rr) * 132 + c4] = o;
                }
            }
            __syncthreads();
        }
    }

    // ================= S2: h2 = relu(h1 @ W2 + b2) -> cat  (chunks 2,3; K=64 each) ====
    {
        int c4 = (tid & 15) * 4;           // 16 col-groups x 4 = 64
        int r2 = (tid >> 4) * 2;           // 16 row-groups x 2 = 32
        float acc[2][4] = {};
        #pragma unroll
        for (int cc = 0; cc < 2; ++cc) {
            int j = 2 + cc;
            issue_chunk(chunk_ptr(j + 1, W1, W2, P1, P2), &lds[((j + 1) & 1) * 4096], tid);
            const float* wb = &lds[(j & 1) * 4096];
            int kb = cc * 64;
            #pragma unroll
            for (int k = 0; k < 64; k += 4) {
                float4 a[2];
                a[0] = *(const float4*)&lds[OFF_H1 + r2 * 132 + kb + k];
                a[1] = *(const float4*)&lds[OFF_H1 + (r2 + 1) * 132 + kb + k];
                #pragma unroll
                for (int kk = 0; kk < 4; ++kk) {
                    float4 w = *(const float4*)&wb[(k + kk) * 64 + c4];
                    #pragma unroll
                    for (int rr = 0; rr < 2; ++rr) {
                        float av = ((const float*)&a[rr])[kk];
                        acc[rr][0] = fmaf(av, w.x, acc[rr][0]);
                        acc[rr][1] = fmaf(av, w.y, acc[rr][1]);
                        acc[rr][2] = fmaf(av, w.z, acc[rr][2]);
                        acc[rr][3] = fmaf(av, w.w, acc[rr][3]);
                    }
                }
            }
            if (cc == 1) {
                float4 bb = *(const float4*)&b2[c4];
                #pragma unroll
                for (int rr = 0; rr < 2; ++rr) {
                    int m = r2 + rr;
                    float4 o;
                    o.x = fmaxf(acc[rr][0] + bb.x, 0.0f);
                    o.y = fmaxf(acc[rr][1] + bb.y, 0.0f);
                    o.z = fmaxf(acc[rr][2] + bb.z, 0.0f);
                    o.w = fmaxf(acc[rr][3] + bb.w, 0.0f);
                    if (m < 24) {
                        *(float4*)&lds[OFF_INP + (m & 7) * 260 + (m >> 3) * 64 + c4] = o;
                    } else if (m == 24) {   // g-head -> broadcast to all 8 rows, cols 192..255
                        #pragma unroll
                        for (int r = 0; r < 8; ++r)
                            *(float4*)&lds[OFF_INP + r * 260 + 192 + c4] = o;
                    }
                }
            }
            __syncthreads();
        }
    }

    // ================= S3: hid = relu(cat @ P1 + bp1)  (chunks 4..11; K=32 each) ======
    {
        int c4 = (tid & 31) * 4;           // 32 col-groups x 4 = 128
        int r  = tid >> 5;                 // 8 rows
        int cro = OFF_INP + r * 260;
        float acc[4] = {};
        #pragma unroll
        for (int cc = 0; cc < 8; ++cc) {
            int j = 4 + cc;
            issue_chunk(chunk_ptr(j + 1, W1, W2, P1, P2), &lds[((j + 1) & 1) * 4096], tid);
            const float* wb = &lds[(j & 1) * 4096];
            int kb = cc * 32;
            #pragma unroll
            for (int k = 0; k < 32; k += 4) {
                float4 a = *(const float4*)&lds[cro + kb + k];
                #pragma unroll
                for (int kk = 0; kk < 4; ++kk) {
                    float4 w = *(const float4*)&wb[(k + kk) * 128 + c4];
                    float av = ((const float*)&a)[kk];
                    acc[0] = fmaf(av, w.x, acc[0]);
                    acc[1] = fmaf(av, w.y, acc[1]);
                    acc[2] = fmaf(av, w.z, acc[2]);
                    acc[3] = fmaf(av, w.w, acc[3]);
                }
            }
            if (cc == 7) {
                float4 bb = *(const float4*)&bp1[c4];
                float4 o;
                o.x = fmaxf(acc[0] + bb.x, 0.0f);
                o.y = fmaxf(acc[1] + bb.y, 0.0f);
                o.z = fmaxf(acc[2] + bb.z, 0.0f);
                o.w = fmaxf(acc[3] + bb.w, 0.0f);
                *(float4*)&lds[OFF_H1 + r * 132 + c4] = o;   // hid (h1 region, h1 is dead)
            }
            __syncthreads();
        }
    }

    // ================= S4: out = relu(hid @ P2 + bp2)  (chunks 12,13; K=64 each) ======
    {
        int c2 = (tid & 31) * 2;           // 32 col-groups x 2 = 64
        int r  = tid >> 5;                 // 8 rows
        float acc[2] = {};
        #pragma unroll
        for (int cc = 0; cc < 2; ++cc) {
            int j = 12 + cc;
            if (cc == 0)
                issue_chunk(chunk_ptr(13, W1, W2, P1, P2), &lds[((j + 1) & 1) * 4096], tid);
            const float* wb = &lds[(j & 1) * 4096];
            int kb = cc * 64;
            #pragma unroll
            for (int k = 0; k < 64; k += 4) {
                float4 a = *(const float4*)&lds[OFF_H1 + r * 132 + kb + k];
                #pragma unroll
                for (int kk = 0; kk < 4; ++kk) {
                    float2 w = *(const float2*)&wb[(k + kk) * 64 + c2];
                    float av = ((const float*)&a)[kk];
                    acc[0] = fmaf(av, w.x, acc[0]);
                    acc[1] = fmaf(av, w.y, acc[1]);
                }
            }
            if (cc == 0) __syncthreads();
        }
        int row = box0 + r;
        if (row < n) {
            float2 bb = *(const float2*)&bp2[c2];
            float2 o;
            o.x = fmaxf(acc[0] + bb.x, 0.0f);
            o.y = fmaxf(acc[1] + bb.y, 0.0f);
            *(float2*)&out[(size_t)row * 64 + c2] = o;
        }
    }
}

extern "C" void kernel_launch(void* const* d_in, const int* in_sizes, int n_in,
                              void* d_out, int out_size, void* d_ws, size_t ws_size,
                              hipStream_t stream) {
    const float* fm    = (const float*)d_in[0];
    const float* boxes = (const float*)d_in[1];
    const float* W1    = (const float*)d_in[2];
    const float* b1    = (const float*)d_in[3];
    const float* W2    = (const float*)d_in[4];
    const float* b2    = (const float*)d_in[5];
    const float* P1    = (const float*)d_in[6];
    const float* bp1   = (const float*)d_in[7];
    const float* P2    = (const float*)d_in[8];
    const float* bp2   = (const float*)d_in[9];
    float* ws = (float*)d_ws;
    __half* fmT     = (__half*)(ws + WS_FMT);
    float* gpartial = ws + WS_GPART;
    float* g        = ws + WS_G;
    int*   perm     = (int*)(ws + WS_PERM);
    float* pooled   = ws + WS_POOL;
    float* out = (float*)d_out;
    int n = in_sizes[1] / 4;   // 4000 boxes

    k_prep<<<961, 256, 0, stream>>>(fm, fmT, gpartial, boxes, perm, n);
    k_pool<<<n, 256, 0, stream>>>(fmT, boxes, perm, gpartial, g, pooled);
    k_mlp<<<(n + 7) / 8, 256, 0, stream>>>(pooled, g, W1, b1, W2, b2,
                                           P1, bp1, P2, bp2, out, n);
}

// Round 2
// 167.060 us; speedup vs baseline: 1.0529x; 1.0529x over previous
//
#include <hip/hip_runtime.h>
#include <hip/hip_fp16.h>

#define FH 240
#define FW 240
#define NSAMP 179   // 9 + 49 + 121
constexpr float IMG = 960.0f;

// ---------------- ws layout (floats) ----------------
static constexpr int WS_FMT   = 0;        // fmT fp16 [240][240][64] -> 1,843,200 float slots
static constexpr int WS_GPART = 1843200;  // gpartial [960][64]
static constexpr int WS_G     = 1904640;  // g [64] (pre-scaled by 1/57600)
static constexpr int WS_PERM  = 1904704;  // perm [4000] ints
static constexpr int WS_POOL  = 1908736;  // pooled [N][192]

// ---------- Kernel 1: blocks 0..959 transpose fm -> fp16 fmT + channel partials;
//                      block 960: counting-sort boxes by (cy,cx) buckets -> perm ----------
__global__ __launch_bounds__(256) void k_prep(const float* __restrict__ fm,
                                              __half* __restrict__ fmT,
                                              float* __restrict__ gpartial,
                                              const float* __restrict__ boxes,
                                              int* __restrict__ perm, int n) {
    __shared__ float tile[64][65];
    __shared__ int hist[256];
    __shared__ int offs[256];
    int bid = blockIdx.x;
    int tid = threadIdx.x;

    if (bid < 960) {
        int y  = bid >> 2;
        int x0 = (bid & 3) * 64;
        int lane = tid & 63;
        int wv   = tid >> 6;
        int x = x0 + lane;
        bool xin = (x < FW);
        #pragma unroll
        for (int k = 0; k < 16; ++k) {
            int c = wv + k * 4;
            tile[c][lane] = xin ? fm[c * (FH * FW) + y * FW + x] : 0.0f;
        }
        __syncthreads();

        if (tid < 64) {
            float s = 0.0f;
            #pragma unroll
            for (int i = 0; i < 64; ++i) s += tile[tid][i];
            gpartial[bid * 64 + tid] = s;
        }

        #pragma unroll
        for (int it = 0; it < 2; ++it) {
            int idx = tid + it * 256;       // 0..511
            int xl  = idx >> 3;             // 0..63
            int co  = (idx & 7) * 8;        // 0,8,...,56
            int xx  = x0 + xl;
            if (xx < FW) {
                union { float4 f4; __half2 h2[4]; } u;
                #pragma unroll
                for (int i = 0; i < 4; ++i)
                    u.h2[i] = __floats2half2_rn(tile[co + 2*i][xl], tile[co + 2*i + 1][xl]);
                *(float4*)&fmT[((size_t)(y * FW + xx)) * 64 + co] = u.f4;
            }
        }
    } else {
        // ---- counting sort of boxes by (cy, cx) 16x16 buckets ----
        hist[tid] = 0;
        __syncthreads();
        for (int i = tid; i < n; i += 256) {
            float cy = (boxes[i * 4 + 1] + boxes[i * 4 + 3]) * 0.5f;
            float cx = (boxes[i * 4 + 0] + boxes[i * 4 + 2]) * 0.5f;
            int by = min(15, max(0, (int)(cy * (16.0f / 960.0f))));
            int bx = min(15, max(0, (int)(cx * (16.0f / 960.0f))));
            atomicAdd(&hist[by * 16 + bx], 1);
        }
        __syncthreads();
        offs[tid] = hist[tid];
        __syncthreads();
        for (int st = 1; st < 256; st <<= 1) {
            int t2 = (tid >= st) ? offs[tid - st] : 0;
            __syncthreads();
            offs[tid] += t2;
            __syncthreads();
        }
        hist[tid] = offs[tid] - hist[tid];     // exclusive start per bucket
        __syncthreads();
        for (int i = tid; i < n; i += 256) {
            float cy = (boxes[i * 4 + 1] + boxes[i * 4 + 3]) * 0.5f;
            float cx = (boxes[i * 4 + 0] + boxes[i * 4 + 2]) * 0.5f;
            int by = min(15, max(0, (int)(cy * (16.0f / 960.0f))));
            int bx = min(15, max(0, (int)(cx * (16.0f / 960.0f))));
            int pos = atomicAdd(&hist[by * 16 + bx], 1);
            perm[pos] = i;
        }
    }
}

// ---------- Kernel 2: ROI bilinear pooling (unchanged, proven) ----------
__device__ __forceinline__ void acc8(float* a, const __half* __restrict__ base,
                                     int off, int c8, float w) {
    float4 raw = *(const float4*)(base + off + c8);   // 8 fp16
    const __half2* h = (const __half2*)&raw;
    #pragma unroll
    for (int i = 0; i < 4; ++i) {
        float2 f = __half22float2(h[i]);
        a[2*i]     = fmaf(w, f.x, a[2*i]);
        a[2*i + 1] = fmaf(w, f.y, a[2*i + 1]);
    }
}

__global__ __launch_bounds__(256) void k_pool(const __half* __restrict__ fmT,
                                              const float* __restrict__ boxes,
                                              const int* __restrict__ perm,
                                              const float* __restrict__ gpartial,
                                              float* __restrict__ g,
                                              float* __restrict__ pooled) {
    __shared__ int   smp[NSAMP * 8];        // 5728 B
    __shared__ float part[64 * 33];         // 8448 B

    int tid = threadIdx.x;

    if (blockIdx.x == 0) {
        int c = tid & 63, q = tid >> 6;
        float s = 0.0f;
        for (int i = q * 240; i < q * 240 + 240; ++i) s += gpartial[i * 64 + c];
        part[tid] = s;
        __syncthreads();
        if (tid < 64)
            g[tid] = (part[tid] + part[64 + tid] + part[128 + tid] + part[192 + tid]) * (1.0f / 57600.0f);
        __syncthreads();
    }

    int box = perm[blockIdx.x];

    if (tid < NSAMP) {
        float bx1 = boxes[box * 4 + 0], by1 = boxes[box * 4 + 1];
        float bx2 = boxes[box * 4 + 2], by2 = boxes[box * 4 + 3];
        float x1n = (bx1 / IMG) * 2.0f - 1.0f;
        float y1n = (by1 / IMG) * 2.0f - 1.0f;
        float x2n = (bx2 / IMG) * 2.0f - 1.0f;
        float y2n = (by2 / IMG) * 2.0f - 1.0f;
        float cx = (x1n + x2n) * 0.5f, cy = (y1n + y2n) * 0.5f;
        float w2 = fmaxf(x2n - x1n, 1e-6f) * 0.5f;
        float h2 = fmaxf(y2n - y1n, 1e-6f) * 0.5f;
        int S, s;
        if (tid < 9)       { S = 3;  s = tid; }
        else if (tid < 58) { S = 7;  s = tid - 9; }
        else               { S = 11; s = tid - 58; }
        int i = s / S;
        int j = s - i * S;
        float Sf = (float)S;
        float bj = (2.0f * (float)j + 1.0f) / Sf - 1.0f;
        float bi = (2.0f * (float)i + 1.0f) / Sf - 1.0f;
        float gx = w2 * bj + cx;
        float gy = h2 * bi + cy;
        float ix = ((gx + 1.0f) * 240.0f - 1.0f) * 0.5f;
        float iy = ((gy + 1.0f) * 240.0f - 1.0f) * 0.5f;
        float x0f = floorf(ix), y0f = floorf(iy);
        float dx = ix - x0f,    dy = iy - y0f;
        int x0 = (int)x0f, y0 = (int)y0f;
        int x1 = x0 + 1,   y1 = y0 + 1;
        float inv = 1.0f / (Sf * Sf);
        float wx0 = (x0 >= 0 && x0 < FW) ? (1.0f - dx) : 0.0f;
        float wx1 = (x1 >= 0 && x1 < FW) ? dx          : 0.0f;
        float wy0 = (y0 >= 0 && y0 < FH) ? (1.0f - dy) : 0.0f;
        float wy1 = (y1 >= 0 && y1 < FH) ? dy          : 0.0f;
        int x0c = min(max(x0, 0), FW - 1), x1c = min(max(x1, 0), FW - 1);
        int y0c = min(max(y0, 0), FH - 1), y1c = min(max(y1, 0), FH - 1);
        int r0 = y0c * FW, r1 = y1c * FW;
        smp[tid * 8 + 0] = (r0 + x0c) * 64;
        smp[tid * 8 + 1] = (r0 + x1c) * 64;
        smp[tid * 8 + 2] = (r1 + x0c) * 64;
        smp[tid * 8 + 3] = (r1 + x1c) * 64;
        float* wp = (float*)&smp[tid * 8 + 4];
        wp[0] = wx0 * wy0 * inv;
        wp[1] = wx1 * wy0 * inv;
        wp[2] = wx0 * wy1 * inv;
        wp[3] = wx1 * wy1 * inv;
    }
    __syncthreads();

    int slot = tid >> 3, l = tid & 7, c8 = l << 3;
    const int start_[3] = {0, 9, 58};
    const int end_[3]   = {9, 58, NSAMP};

    #pragma unroll
    for (int sc = 0; sc < 3; ++sc) {
        float a[8];
        #pragma unroll
        for (int k = 0; k < 8; ++k) a[k] = 0.0f;
        for (int s = start_[sc] + slot; s < end_[sc]; s += 32) {
            int4   bo = *(const int4*)  &smp[s * 8];
            float4 wv = *(const float4*)&smp[s * 8 + 4];
            acc8(a, fmT, bo.x, c8, wv.x);
            acc8(a, fmT, bo.y, c8, wv.y);
            acc8(a, fmT, bo.z, c8, wv.z);
            acc8(a, fmT, bo.w, c8, wv.w);
        }
        #pragma unroll
        for (int i = 0; i < 8; ++i)
            part[(c8 + i) * 33 + slot] = a[i];
        __syncthreads();
        if (tid < 64) {
            float sum = 0.0f;
            #pragma unroll
            for (int q = 0; q < 32; ++q) sum += part[tid * 33 + q];
            pooled[(size_t)box * 192 + sc * 64 + tid] = sum;
        }
        __syncthreads();
    }
}

// ---------- Kernel 3: heads + final MLP ----------
// v2: 4 boxes/block -> 1000 blocks (~4 blocks/CU, 16 waves/CU) to fix the
// grid-capped occupancy that left the 500-block version latency-bound.
// Full-K accumulation in every stage (no K-split partial buffers, no reduce
// passes): LDS 74 KB -> 12.6 KB, barriers 10 -> 5. Weights stay as plain
// global float4/float2 loads (L2/L3-resident; FETCH was 2.6 MB at 500 blocks).
// Row map (13 live rows, padded to 16): m = sc*4 + rb for rb in 0..3 boxes,
// sc in 0..2 scales; m = 12 is the g row; rows 13..15 zero.
// LDS aliasing: regionA = inp[16][64] (1024) then cat[4][260] (1040, after S1);
//               regionB = h1[16][132] (2112) then hid[4][132] (after S2).
__global__ __launch_bounds__(256) void k_mlp(const float* __restrict__ pooled,
                                             const float* __restrict__ g,
                                             const float* __restrict__ W1, const float* __restrict__ b1,
                                             const float* __restrict__ W2, const float* __restrict__ b2,
                                             const float* __restrict__ P1, const float* __restrict__ bp1,
                                             const float* __restrict__ P2, const float* __restrict__ bp2,
                                             float* __restrict__ out, int n) {
    __shared__ float lds[1040 + 2112];     // 12,608 B
    float* inp = lds;                      // [16][64]
    float* cat = lds;                      // [4][260]  (aliases inp, live after S1)
    float* h1  = lds + 1040;               // [16][132]
    float* hid = lds + 1040;               // [4][132]  (aliases h1, live after S2)
    int tid = threadIdx.x;
    int box0 = blockIdx.x * 4;

    // ---- stage inputs ----
    if (tid < 192) {                       // 12 rows x 16 float4
        int rb  = tid / 48;                // box 0..3
        int rem = tid - rb * 48;
        int sc  = rem >> 4;                // scale 0..2
        int cq  = rem & 15;
        float4 v = make_float4(0, 0, 0, 0);
        if (box0 + rb < n)
            v = *(const float4*)&pooled[(size_t)(box0 + rb) * 192 + sc * 64 + cq * 4];
        *(float4*)&inp[(sc * 4 + rb) * 64 + cq * 4] = v;
    } else if (tid < 208) {                // g row (row 12)
        int cq = tid - 192;
        *(float4*)&inp[12 * 64 + cq * 4] = *(const float4*)&g[cq * 4];
    } else {                               // zero rows 13..15 (192 floats, 48 thr)
        int i = tid - 208;
        *(float4*)&inp[13 * 64 + i * 4] = make_float4(0, 0, 0, 0);
    }
    __syncthreads();

    // ---- S1: h1 = relu(inp @ W1 + b1)   [16x64]@[64x128] ----
    {
        int c4 = (tid & 31) * 4;           // 32 col-groups x 4 = 128
        int r2 = (tid >> 5) * 2;           // 8 row-groups x 2 = 16
        float acc[2][4] = {};
        #pragma unroll
        for (int k = 0; k < 64; k += 4) {
            float4 a0 = *(const float4*)&inp[r2 * 64 + k];
            float4 a1 = *(const float4*)&inp[(r2 + 1) * 64 + k];
            #pragma unroll
            for (int kk = 0; kk < 4; ++kk) {
                float4 w = *(const float4*)&W1[(k + kk) * 128 + c4];
                float v0 = ((const float*)&a0)[kk];
                float v1 = ((const float*)&a1)[kk];
                acc[0][0] = fmaf(v0, w.x, acc[0][0]);
                acc[0][1] = fmaf(v0, w.y, acc[0][1]);
                acc[0][2] = fmaf(v0, w.z, acc[0][2]);
                acc[0][3] = fmaf(v0, w.w, acc[0][3]);
                acc[1][0] = fmaf(v1, w.x, acc[1][0]);
                acc[1][1] = fmaf(v1, w.y, acc[1][1]);
                acc[1][2] = fmaf(v1, w.z, acc[1][2]);
                acc[1][3] = fmaf(v1, w.w, acc[1][3]);
            }
        }
        float4 bb = *(const float4*)&b1[c4];
        #pragma unroll
        for (int rr = 0; rr < 2; ++rr) {
            float4 o;
            o.x = fmaxf(acc[rr][0] + bb.x, 0.0f);
            o.y = fmaxf(acc[rr][1] + bb.y, 0.0f);
            o.z = fmaxf(acc[rr][2] + bb.z, 0.0f);
            o.w = fmaxf(acc[rr][3] + bb.w, 0.0f);
            *(float4*)&h1[(r2 + rr) * 132 + c4] = o;
        }
    }
    __syncthreads();

    // ---- S2: h2 = relu(h1 @ W2 + b2) -> cat   [16x128]@[128x64] ----
    {
        int c4 = (tid & 15) * 4;           // 16 col-groups x 4 = 64
        int r  = tid >> 4;                 // 16 rows
        float acc[4] = {};
        #pragma unroll
        for (int k = 0; k < 128; k += 4) {
            float4 a = *(const float4*)&h1[r * 132 + k];
            #pragma unroll
            for (int kk = 0; kk < 4; ++kk) {
                float4 w = *(const float4*)&W2[(k + kk) * 64 + c4];
                float av = ((const float*)&a)[kk];
                acc[0] = fmaf(av, w.x, acc[0]);
                acc[1] = fmaf(av, w.y, acc[1]);
                acc[2] = fmaf(av, w.z, acc[2]);
                acc[3] = fmaf(av, w.w, acc[3]);
            }
        }
        float4 bb = *(const float4*)&b2[c4];
        float4 o;
        o.x = fmaxf(acc[0] + bb.x, 0.0f);
        o.y = fmaxf(acc[1] + bb.y, 0.0f);
        o.z = fmaxf(acc[2] + bb.z, 0.0f);
        o.w = fmaxf(acc[3] + bb.w, 0.0f);
        __syncthreads();                   // inp reads done before cat overwrites
        if (r < 12) {
            *(float4*)&cat[(r & 3) * 260 + (r >> 2) * 64 + c4] = o;   // rb=r&3, sc=r>>2
        } else if (r == 12) {
            #pragma unroll
            for (int rb = 0; rb < 4; ++rb)
                *(float4*)&cat[rb * 260 + 192 + c4] = o;
        }
    }
    __syncthreads();

    // ---- S3: hid = relu(cat @ P1 + bp1)   [4x256]@[256x128] ----
    {
        int c2 = (tid & 63) * 2;           // 64 col-groups x 2 = 128
        int r  = tid >> 6;                 // 4 rows
        float a0 = 0.0f, a1 = 0.0f;
        #pragma unroll 16
        for (int k = 0; k < 256; k += 4) {
            float4 a = *(const float4*)&cat[r * 260 + k];
            #pragma unroll
            for (int kk = 0; kk < 4; ++kk) {
                float2 w = *(const float2*)&P1[(k + kk) * 128 + c2];
                float av = ((const float*)&a)[kk];
                a0 = fmaf(av, w.x, a0);
                a1 = fmaf(av, w.y, a1);
            }
        }
        float2 bb = *(const float2*)&bp1[c2];
        float2 o;
        o.x = fmaxf(a0 + bb.x, 0.0f);
        o.y = fmaxf(a1 + bb.y, 0.0f);
        __syncthreads();                   // h1 reads done before hid overwrites
        *(float2*)&hid[r * 132 + c2] = o;
    }
    __syncthreads();

    // ---- S4: out = relu(hid @ P2 + bp2)   [4x128]@[128x64] ----
    {
        int c = tid & 63;                  // 64 cols
        int r = tid >> 6;                  // 4 rows
        float acc = 0.0f;
        #pragma unroll
        for (int k = 0; k < 128; k += 4) {
            float4 a = *(const float4*)&hid[r * 132 + k];
            acc = fmaf(a.x, P2[(k + 0) * 64 + c], acc);
            acc = fmaf(a.y, P2[(k + 1) * 64 + c], acc);
            acc = fmaf(a.z, P2[(k + 2) * 64 + c], acc);
            acc = fmaf(a.w, P2[(k + 3) * 64 + c], acc);
        }
        int row = box0 + r;
        if (row < n)
            out[(size_t)row * 64 + c] = fmaxf(acc + bp2[c], 0.0f);
    }
}

extern "C" void kernel_launch(void* const* d_in, const int* in_sizes, int n_in,
                              void* d_out, int out_size, void* d_ws, size_t ws_size,
                              hipStream_t stream) {
    const float* fm    = (const float*)d_in[0];
    const float* boxes = (const float*)d_in[1];
    const float* W1    = (const float*)d_in[2];
    const float* b1    = (const float*)d_in[3];
    const float* W2    = (const float*)d_in[4];
    const float* b2    = (const float*)d_in[5];
    const float* P1    = (const float*)d_in[6];
    const float* bp1   = (const float*)d_in[7];
    const float* P2    = (const float*)d_in[8];
    const float* bp2   = (const float*)d_in[9];
    float* ws = (float*)d_ws;
    __half* fmT     = (__half*)(ws + WS_FMT);
    float* gpartial = ws + WS_GPART;
    float* g        = ws + WS_G;
    int*   perm     = (int*)(ws + WS_PERM);
    float* pooled   = ws + WS_POOL;
    float* out = (float*)d_out;
    int n = in_sizes[1] / 4;   // 4000 boxes

    k_prep<<<961, 256, 0, stream>>>(fm, fmT, gpartial, boxes, perm, n);
    k_pool<<<n, 256, 0, stream>>>(fmT, boxes, perm, gpartial, g, pooled);
    k_mlp<<<(n + 3) / 4, 256, 0, stream>>>(pooled, g, W1, b1, W2, b2,
                                           P1, bp1, P2, bp2, out, n);
}

// Round 3
// 148.075 us; speedup vs baseline: 1.1879x; 1.1282x over previous
//
#include <hip/hip_runtime.h>
#include <hip/hip_fp16.h>

#define FH 240
#define FW 240
#define NSAMP 179   // 9 + 49 + 121
constexpr float IMG = 960.0f;

// ---------------- ws layout (floats) ----------------
static constexpr int WS_FMT   = 0;        // fmT fp16 [240][240][64] -> 1,843,200 float slots
                                          // (dead after k_pool; reused as hcat [3n][64])
static constexpr int WS_GPART = 1843200;  // gpartial [960][64]
static constexpr int WS_G     = 1904640;  // g [64] (pre-scaled by 1/57600)
static constexpr int WS_PERM  = 1904704;  // perm [4000] ints
static constexpr int WS_POOL  = 1908736;  // pooled [3n][64] ; hidg [128] right after

// ---------- Kernel 1: blocks 0..959 transpose fm -> fp16 fmT + channel partials;
//                      block 960: counting-sort boxes by (cy,cx) buckets -> perm ----------
__global__ __launch_bounds__(256) void k_prep(const float* __restrict__ fm,
                                              __half* __restrict__ fmT,
                                              float* __restrict__ gpartial,
                                              const float* __restrict__ boxes,
                                              int* __restrict__ perm, int n) {
    __shared__ float tile[64][65];
    __shared__ int hist[256];
    __shared__ int offs[256];
    int bid = blockIdx.x;
    int tid = threadIdx.x;

    if (bid < 960) {
        int y  = bid >> 2;
        int x0 = (bid & 3) * 64;
        int lane = tid & 63;
        int wv   = tid >> 6;
        int x = x0 + lane;
        bool xin = (x < FW);
        #pragma unroll
        for (int k = 0; k < 16; ++k) {
            int c = wv + k * 4;
            tile[c][lane] = xin ? fm[c * (FH * FW) + y * FW + x] : 0.0f;
        }
        __syncthreads();

        if (tid < 64) {
            float s = 0.0f;
            #pragma unroll
            for (int i = 0; i < 64; ++i) s += tile[tid][i];
            gpartial[bid * 64 + tid] = s;
        }

        #pragma unroll
        for (int it = 0; it < 2; ++it) {
            int idx = tid + it * 256;       // 0..511
            int xl  = idx >> 3;             // 0..63
            int co  = (idx & 7) * 8;        // 0,8,...,56
            int xx  = x0 + xl;
            if (xx < FW) {
                union { float4 f4; __half2 h2[4]; } u;
                #pragma unroll
                for (int i = 0; i < 4; ++i)
                    u.h2[i] = __floats2half2_rn(tile[co + 2*i][xl], tile[co + 2*i + 1][xl]);
                *(float4*)&fmT[((size_t)(y * FW + xx)) * 64 + co] = u.f4;
            }
        }
    } else {
        // ---- counting sort of boxes by (cy, cx) 16x16 buckets ----
        hist[tid] = 0;
        __syncthreads();
        for (int i = tid; i < n; i += 256) {
            float cy = (boxes[i * 4 + 1] + boxes[i * 4 + 3]) * 0.5f;
            float cx = (boxes[i * 4 + 0] + boxes[i * 4 + 2]) * 0.5f;
            int by = min(15, max(0, (int)(cy * (16.0f / 960.0f))));
            int bx = min(15, max(0, (int)(cx * (16.0f / 960.0f))));
            atomicAdd(&hist[by * 16 + bx], 1);
        }
        __syncthreads();
        offs[tid] = hist[tid];
        __syncthreads();
        for (int st = 1; st < 256; st <<= 1) {
            int t2 = (tid >= st) ? offs[tid - st] : 0;
            __syncthreads();
            offs[tid] += t2;
            __syncthreads();
        }
        hist[tid] = offs[tid] - hist[tid];     // exclusive start per bucket
        __syncthreads();
        for (int i = tid; i < n; i += 256) {
            float cy = (boxes[i * 4 + 1] + boxes[i * 4 + 3]) * 0.5f;
            float cx = (boxes[i * 4 + 0] + boxes[i * 4 + 2]) * 0.5f;
            int by = min(15, max(0, (int)(cy * (16.0f / 960.0f))));
            int bx = min(15, max(0, (int)(cx * (16.0f / 960.0f))));
            int pos = atomicAdd(&hist[by * 16 + bx], 1);
            perm[pos] = i;
        }
    }
}

// ---------- Kernel 2: ROI bilinear pooling (proven) + block 0: g, g-head, hidg ----------
__device__ __forceinline__ void acc8(float* a, const __half* __restrict__ base,
                                     int off, int c8, float w) {
    float4 raw = *(const float4*)(base + off + c8);   // 8 fp16
    const __half2* h = (const __half2*)&raw;
    #pragma unroll
    for (int i = 0; i < 4; ++i) {
        float2 f = __half22float2(h[i]);
        a[2*i]     = fmaf(w, f.x, a[2*i]);
        a[2*i + 1] = fmaf(w, f.y, a[2*i + 1]);
    }
}

__global__ __launch_bounds__(256) void k_pool(const __half* __restrict__ fmT,
                                              const float* __restrict__ boxes,
                                              const int* __restrict__ perm,
                                              const float* __restrict__ gpartial,
                                              float* __restrict__ g,
                                              float* __restrict__ pooled,
                                              const float* __restrict__ W1, const float* __restrict__ b1,
                                              const float* __restrict__ W2, const float* __restrict__ b2,
                                              const float* __restrict__ P1, const float* __restrict__ bp1,
                                              float* __restrict__ hidg) {
    __shared__ int   smp[NSAMP * 8];        // 5728 B
    __shared__ float part[64 * 33];         // 8448 B
    __shared__ float gsh[64];

    int tid = threadIdx.x;

    if (blockIdx.x == 0) {
        int c = tid & 63, q = tid >> 6;
        float s = 0.0f;
        for (int i = q * 240; i < q * 240 + 240; ++i) s += gpartial[i * 64 + c];
        part[tid] = s;
        __syncthreads();
        if (tid < 64) {
            float v = (part[tid] + part[64 + tid] + part[128 + tid] + part[192 + tid]) * (1.0f / 57600.0f);
            g[tid] = v;
            gsh[tid] = v;
        }
        __syncthreads();
    }

    int box = perm[blockIdx.x];

    if (tid < NSAMP) {
        float bx1 = boxes[box * 4 + 0], by1 = boxes[box * 4 + 1];
        float bx2 = boxes[box * 4 + 2], by2 = boxes[box * 4 + 3];
        float x1n = (bx1 / IMG) * 2.0f - 1.0f;
        float y1n = (by1 / IMG) * 2.0f - 1.0f;
        float x2n = (bx2 / IMG) * 2.0f - 1.0f;
        float y2n = (by2 / IMG) * 2.0f - 1.0f;
        float cx = (x1n + x2n) * 0.5f, cy = (y1n + y2n) * 0.5f;
        float w2 = fmaxf(x2n - x1n, 1e-6f) * 0.5f;
        float h2 = fmaxf(y2n - y1n, 1e-6f) * 0.5f;
        int S, s;
        if (tid < 9)       { S = 3;  s = tid; }
        else if (tid < 58) { S = 7;  s = tid - 9; }
        else               { S = 11; s = tid - 58; }
        int i = s / S;
        int j = s - i * S;
        float Sf = (float)S;
        float bj = (2.0f * (float)j + 1.0f) / Sf - 1.0f;
        float bi = (2.0f * (float)i + 1.0f) / Sf - 1.0f;
        float gx = w2 * bj + cx;
        float gy = h2 * bi + cy;
        float ix = ((gx + 1.0f) * 240.0f - 1.0f) * 0.5f;
        float iy = ((gy + 1.0f) * 240.0f - 1.0f) * 0.5f;
        float x0f = floorf(ix), y0f = floorf(iy);
        float dx = ix - x0f,    dy = iy - y0f;
        int x0 = (int)x0f, y0 = (int)y0f;
        int x1 = x0 + 1,   y1 = y0 + 1;
        float inv = 1.0f / (Sf * Sf);
        float wx0 = (x0 >= 0 && x0 < FW) ? (1.0f - dx) : 0.0f;
        float wx1 = (x1 >= 0 && x1 < FW) ? dx          : 0.0f;
        float wy0 = (y0 >= 0 && y0 < FH) ? (1.0f - dy) : 0.0f;
        float wy1 = (y1 >= 0 && y1 < FH) ? dy          : 0.0f;
        int x0c = min(max(x0, 0), FW - 1), x1c = min(max(x1, 0), FW - 1);
        int y0c = min(max(y0, 0), FH - 1), y1c = min(max(y1, 0), FH - 1);
        int r0 = y0c * FW, r1 = y1c * FW;
        smp[tid * 8 + 0] = (r0 + x0c) * 64;
        smp[tid * 8 + 1] = (r0 + x1c) * 64;
        smp[tid * 8 + 2] = (r1 + x0c) * 64;
        smp[tid * 8 + 3] = (r1 + x1c) * 64;
        float* wp = (float*)&smp[tid * 8 + 4];
        wp[0] = wx0 * wy0 * inv;
        wp[1] = wx1 * wy0 * inv;
        wp[2] = wx0 * wy1 * inv;
        wp[3] = wx1 * wy1 * inv;
    }
    __syncthreads();

    int slot = tid >> 3, l = tid & 7, c8 = l << 3;
    const int start_[3] = {0, 9, 58};
    const int end_[3]   = {9, 58, NSAMP};

    #pragma unroll
    for (int sc = 0; sc < 3; ++sc) {
        float a[8];
        #pragma unroll
        for (int k = 0; k < 8; ++k) a[k] = 0.0f;
        for (int s = start_[sc] + slot; s < end_[sc]; s += 32) {
            int4   bo = *(const int4*)  &smp[s * 8];
            float4 wv = *(const float4*)&smp[s * 8 + 4];
            acc8(a, fmT, bo.x, c8, wv.x);
            acc8(a, fmT, bo.y, c8, wv.y);
            acc8(a, fmT, bo.z, c8, wv.z);
            acc8(a, fmT, bo.w, c8, wv.w);
        }
        #pragma unroll
        for (int i = 0; i < 8; ++i)
            part[(c8 + i) * 33 + slot] = a[i];
        __syncthreads();
        if (tid < 64) {
            float sum = 0.0f;
            #pragma unroll
            for (int q = 0; q < 32; ++q) sum += part[tid * 33 + q];
            pooled[(size_t)box * 192 + sc * 64 + tid] = sum;
        }
        __syncthreads();
    }

    // ---- block 0 tail: g-head + fold its P1[192:256] contribution into hidg bias ----
    if (blockIdx.x == 0) {
        __syncthreads();
        if (tid < 128) {                       // h1g = relu(g @ W1 + b1)
            float a = b1[tid];
            for (int k = 0; k < 64; ++k) a = fmaf(gsh[k], W1[k * 128 + tid], a);
            part[tid] = fmaxf(a, 0.0f);
        }
        __syncthreads();
        if (tid < 64) {                        // hg = relu(h1g @ W2 + b2)
            float a = b2[tid];
            for (int k = 0; k < 128; ++k) a = fmaf(part[k], W2[k * 64 + tid], a);
            part[128 + tid] = fmaxf(a, 0.0f);
        }
        __syncthreads();
        if (tid < 128) {                       // hidg = bp1 + hg @ P1[192:256]  (pre-relu bias)
            float a = bp1[tid];
            for (int k = 0; k < 64; ++k) a = fmaf(part[128 + k], P1[(192 + k) * 128 + tid], a);
            hidg[tid] = a;
        }
    }
}

// ---------- Kernel 3a: head GEMM over ALL rows (M = 3n = 12000) ----------
// h2 = relu(relu(x @ W1 + b1) @ W2 + b2), x = pooled rows of 64.
// 16 rows/block -> 750 blocks. All weight loads float4; S1: 8 acc chains/thread,
// S2: 4 chains. hcat row r (= box*3+sc) is contiguous -> hcat[box] is [192].
__global__ __launch_bounds__(256) void k_head(const float* __restrict__ pooled,
                                              const float* __restrict__ W1, const float* __restrict__ b1,
                                              const float* __restrict__ W2, const float* __restrict__ b2,
                                              float* __restrict__ hcat, int nrows) {
    __shared__ float x[16][68];
    __shared__ float h1[16][132];
    int tid = threadIdx.x;
    int row0 = blockIdx.x * 16;

    {   // stage x: 16 rows x 16 float4 = 256 -> one per thread
        int r = tid >> 4, q = (tid & 15) * 4;
        int gr = row0 + r;
        float4 v = make_float4(0, 0, 0, 0);
        if (gr < nrows) v = *(const float4*)&pooled[(size_t)gr * 64 + q];
        *(float4*)&x[r][q] = v;
    }
    __syncthreads();

    // ---- S1: h1 = relu(x @ W1 + b1)   [16x64]@[64x128] ----
    {
        int c4 = (tid & 31) * 4;           // 32 col-groups x 4 = 128
        int r2 = (tid >> 5) * 2;           // 8 row-groups x 2 = 16
        float acc[2][4] = {};
        #pragma unroll
        for (int k = 0; k < 64; k += 4) {
            float4 a0 = *(const float4*)&x[r2][k];
            float4 a1 = *(const float4*)&x[r2 + 1][k];
            #pragma unroll
            for (int kk = 0; kk < 4; ++kk) {
                float4 w = *(const float4*)&W1[(k + kk) * 128 + c4];
                float v0 = ((const float*)&a0)[kk];
                float v1 = ((const float*)&a1)[kk];
                acc[0][0] = fmaf(v0, w.x, acc[0][0]);
                acc[0][1] = fmaf(v0, w.y, acc[0][1]);
                acc[0][2] = fmaf(v0, w.z, acc[0][2]);
                acc[0][3] = fmaf(v0, w.w, acc[0][3]);
                acc[1][0] = fmaf(v1, w.x, acc[1][0]);
                acc[1][1] = fmaf(v1, w.y, acc[1][1]);
                acc[1][2] = fmaf(v1, w.z, acc[1][2]);
                acc[1][3] = fmaf(v1, w.w, acc[1][3]);
            }
        }
        float4 bb = *(const float4*)&b1[c4];
        #pragma unroll
        for (int rr = 0; rr < 2; ++rr) {
            float4 o;
            o.x = fmaxf(acc[rr][0] + bb.x, 0.0f);
            o.y = fmaxf(acc[rr][1] + bb.y, 0.0f);
            o.z = fmaxf(acc[rr][2] + bb.z, 0.0f);
            o.w = fmaxf(acc[rr][3] + bb.w, 0.0f);
            *(float4*)&h1[r2 + rr][c4] = o;
        }
    }
    __syncthreads();

    // ---- S2: h2 = relu(h1 @ W2 + b2) -> hcat   [16x128]@[128x64] ----
    {
        int c4 = (tid & 15) * 4;           // 16 col-groups x 4 = 64
        int r  = tid >> 4;                 // 16 rows
        float acc[4] = {};
        #pragma unroll
        for (int k = 0; k < 128; k += 4) {
            float4 a = *(const float4*)&h1[r][k];
            #pragma unroll
            for (int kk = 0; kk < 4; ++kk) {
                float4 w = *(const float4*)&W2[(k + kk) * 64 + c4];
                float av = ((const float*)&a)[kk];
                acc[0] = fmaf(av, w.x, acc[0]);
                acc[1] = fmaf(av, w.y, acc[1]);
                acc[2] = fmaf(av, w.z, acc[2]);
                acc[3] = fmaf(av, w.w, acc[3]);
            }
        }
        float4 bb = *(const float4*)&b2[c4];
        float4 o;
        o.x = fmaxf(acc[0] + bb.x, 0.0f);
        o.y = fmaxf(acc[1] + bb.y, 0.0f);
        o.z = fmaxf(acc[2] + bb.z, 0.0f);
        o.w = fmaxf(acc[3] + bb.w, 0.0f);
        int gr = row0 + r;
        if (gr < nrows)
            *(float4*)&hcat[(size_t)gr * 64 + c4] = o;
    }
}

// ---------- Kernel 3b: final MLP  out = relu(relu(hcat@P1[0:192] + hidg) @ P2 + bp2) ----------
// 8 boxes/block -> 500 blocks. S3: 4 acc chains/thread, K=192, float4 weights.
__global__ __launch_bounds__(256) void k_tail(const float* __restrict__ hcat,
                                              const float* __restrict__ hidg,
                                              const float* __restrict__ P1,
                                              const float* __restrict__ P2, const float* __restrict__ bp2,
                                              float* __restrict__ out, int n) {
    __shared__ float ct[8][196];
    __shared__ float hid[8][132];
    int tid = threadIdx.x;
    int box0 = blockIdx.x * 8;

    // stage ct: 8 x 48 float4 = 384
    for (int i = tid; i < 384; i += 256) {
        int r = i / 48, q = (i % 48) * 4;
        int b = box0 + r;
        float4 v = make_float4(0, 0, 0, 0);
        if (b < n) v = *(const float4*)&hcat[(size_t)b * 192 + q];
        *(float4*)&ct[r][q] = v;
    }
    __syncthreads();

    // ---- S3: hid = relu(ct @ P1[0:192] + hidg)   [8x192]@[192x128] ----
    {
        int c4 = (tid & 31) * 4;           // 32 col-groups x 4 = 128
        int r  = tid >> 5;                 // 8 rows
        float acc[4] = {};
        #pragma unroll
        for (int k = 0; k < 192; k += 4) {
            float4 a = *(const float4*)&ct[r][k];
            #pragma unroll
            for (int kk = 0; kk < 4; ++kk) {
                float4 w = *(const float4*)&P1[(k + kk) * 128 + c4];
                float av = ((const float*)&a)[kk];
                acc[0] = fmaf(av, w.x, acc[0]);
                acc[1] = fmaf(av, w.y, acc[1]);
                acc[2] = fmaf(av, w.z, acc[2]);
                acc[3] = fmaf(av, w.w, acc[3]);
            }
        }
        float4 hb = *(const float4*)&hidg[c4];
        float4 o;
        o.x = fmaxf(acc[0] + hb.x, 0.0f);
        o.y = fmaxf(acc[1] + hb.y, 0.0f);
        o.z = fmaxf(acc[2] + hb.z, 0.0f);
        o.w = fmaxf(acc[3] + hb.w, 0.0f);
        *(float4*)&hid[r][c4] = o;
    }
    __syncthreads();

    // ---- S4: out = relu(hid @ P2 + bp2)   [8x128]@[128x64] ----
    {
        int c2 = (tid & 31) * 2;           // 32 col-groups x 2 = 64
        int r  = tid >> 5;                 // 8 rows
        float a0 = 0.0f, a1 = 0.0f;
        #pragma unroll
        for (int k = 0; k < 128; k += 4) {
            float4 a = *(const float4*)&hid[r][k];
            #pragma unroll
            for (int kk = 0; kk < 4; ++kk) {
                float2 w = *(const float2*)&P2[(k + kk) * 64 + c2];
                float av = ((const float*)&a)[kk];
                a0 = fmaf(av, w.x, a0);
                a1 = fmaf(av, w.y, a1);
            }
        }
        int row = box0 + r;
        if (row < n) {
            float2 bb = *(const float2*)&bp2[c2];
            float2 o;
            o.x = fmaxf(a0 + bb.x, 0.0f);
            o.y = fmaxf(a1 + bb.y, 0.0f);
            *(float2*)&out[(size_t)row * 64 + c2] = o;
        }
    }
}

extern "C" void kernel_launch(void* const* d_in, const int* in_sizes, int n_in,
                              void* d_out, int out_size, void* d_ws, size_t ws_size,
                              hipStream_t stream) {
    const float* fm    = (const float*)d_in[0];
    const float* boxes = (const float*)d_in[1];
    const float* W1    = (const float*)d_in[2];
    const float* b1    = (const float*)d_in[3];
    const float* W2    = (const float*)d_in[4];
    const float* b2    = (const float*)d_in[5];
    const float* P1    = (const float*)d_in[6];
    const float* bp1   = (const float*)d_in[7];
    const float* P2    = (const float*)d_in[8];
    const float* bp2   = (const float*)d_in[9];
    float* ws = (float*)d_ws;
    __half* fmT     = (__half*)(ws + WS_FMT);
    float* gpartial = ws + WS_GPART;
    float* g        = ws + WS_G;
    int*   perm     = (int*)(ws + WS_PERM);
    float* pooled   = ws + WS_POOL;
    float* out = (float*)d_out;
    int n = in_sizes[1] / 4;   // 4000 boxes
    int nrows = 3 * n;
    float* hidg = ws + WS_POOL + (size_t)nrows * 64;   // [128]
    float* hcat = ws + WS_FMT;                         // reuse fmT region after k_pool

    k_prep<<<961, 256, 0, stream>>>(fm, fmT, gpartial, boxes, perm, n);
    k_pool<<<n, 256, 0, stream>>>(fmT, boxes, perm, gpartial, g, pooled,
                                  W1, b1, W2, b2, P1, bp1, hidg);
    k_head<<<(nrows + 15) / 16, 256, 0, stream>>>(pooled, W1, b1, W2, b2, hcat, nrows);
    k_tail<<<(n + 7) / 8, 256, 0, stream>>>(hcat, hidg, P1, P2, bp2, out, n);
}